// Round 1
// baseline (16966.100 us; speedup 1.0000x reference)
//
#include <hip/hip_runtime.h>
#include <hip/hip_fp16.h>
#include <stdint.h>
#include <stddef.h>

#define Bb 64
#define Ss 1024
#define Ii 512
#define Hh 512
#define G4 2048   // 4*H

typedef _Float16 h16;
typedef _Float16 h16x8 __attribute__((ext_vector_type(8)));
typedef _Float16 h16x2 __attribute__((ext_vector_type(2)));
typedef float    f32x4 __attribute__((ext_vector_type(4)));

__device__ __forceinline__ h16x2 as_h2(unsigned u){ union{unsigned u; h16x2 h;} t; t.u=u; return t.h; }

__device__ __forceinline__ float dot8(uint4 w, uint4 h, float acc){
#if __has_builtin(__builtin_amdgcn_fdot2)
  acc = __builtin_amdgcn_fdot2(as_h2(w.x), as_h2(h.x), acc, false);
  acc = __builtin_amdgcn_fdot2(as_h2(w.y), as_h2(h.y), acc, false);
  acc = __builtin_amdgcn_fdot2(as_h2(w.z), as_h2(h.z), acc, false);
  acc = __builtin_amdgcn_fdot2(as_h2(w.w), as_h2(h.w), acc, false);
#else
  {
    h16x2 a, b;
    a = as_h2(w.x); b = as_h2(h.x); acc += (float)a[0]*(float)b[0] + (float)a[1]*(float)b[1];
    a = as_h2(w.y); b = as_h2(h.y); acc += (float)a[0]*(float)b[0] + (float)a[1]*(float)b[1];
    a = as_h2(w.z); b = as_h2(h.z); acc += (float)a[0]*(float)b[0] + (float)a[1]*(float)b[1];
    a = as_h2(w.w); b = as_h2(h.w); acc += (float)a[0]*(float)b[0] + (float)a[1]*(float)b[1];
  }
#endif
  return acc;
}

__device__ __forceinline__ float sigm(float x){ return 1.0f / (1.0f + __expf(-x)); }
__device__ __forceinline__ float tanh_(float x){
  float e = __expf(-2.0f * fabsf(x));
  float t = (1.0f - e) / (1.0f + e);
  return copysignf(t, x);
}

// ---------------------------------------------------------------------------
// Weight prep: W_xh is (I+H) x 4H row-major fp32.
//  WxT[n][k] = (f16) W_xh[k][n]            for k <  I   (B^T layout for GEMM)
//  Wpk[g][n][kk] = (f16) W_xh[I+8g+kk][n]  for k >= I   (coalesced rec loads)
// ---------------------------------------------------------------------------
__global__ void prep_weights(const float* __restrict__ Wxh,
                             h16* __restrict__ WxT, h16* __restrict__ Wpk){
  int idx = blockIdx.x * 256 + threadIdx.x;
  if (idx >= (Ii + Hh) * G4) return;
  int k = idx / G4, n = idx % G4;        // read Wxh[idx] coalesced
  float w = Wxh[idx];
  if (k < Ii){
    WxT[(size_t)n * Ii + k] = (h16)w;
  } else {
    int kr = k - Ii; int g = kr >> 3, kk = kr & 7;
    Wpk[(((size_t)g * G4) + n) * 8 + kk] = (h16)w;
  }
}

// ---------------------------------------------------------------------------
// zx GEMM: zx[r][n] = sum_k x_row(r)[k] * W_x[k][n], r = b*Tc + sc (chunk rows)
// f16 MFMA 16x16x32, 128x128 tile, 256 threads (4 waves, 2x2 of 64x64).
// ---------------------------------------------------------------------------
#define BM 128
#define BN 128
#define BK 32
#define LDP 48   // padded f16 per LDS row (96 B, 16B-aligned, bank-balanced)

__global__ __launch_bounds__(256) void gemm_zx(const float* __restrict__ x,
                                               const h16* __restrict__ WxT,
                                               float* __restrict__ zx,
                                               int t0, int tclog){
  __shared__ h16 lA[BM][LDP];
  __shared__ h16 lB[BN][LDP];
  const int tid  = threadIdx.x;
  const int lane = tid & 63, wid = tid >> 6;
  const int wm = wid >> 1, wn = wid & 1;
  const int bn0 = blockIdx.x * BN, bm0 = blockIdx.y * BM;

  f32x4 acc[4][4] = {};

  // A staging addresses: 2 threads per row, 16 k each
  const int r_local = tid >> 1;
  const int kh = (tid & 1) * 16;
  const int r = bm0 + r_local;
  const int bidx = r >> tclog;
  const int sc   = r & ((1 << tclog) - 1);
  const float* xrow = x + ((size_t)bidx * Ss + (t0 + sc)) * Ii + kh;

  for (int ks = 0; ks < Ii / BK; ++ks){
    const int k0 = ks * BK;
    __syncthreads();
    // stage A (fp32 -> f16)
    {
      const float* p = xrow + k0;
      f32x4 v0 = *(const f32x4*)(p);
      f32x4 v1 = *(const f32x4*)(p + 4);
      f32x4 v2 = *(const f32x4*)(p + 8);
      f32x4 v3 = *(const f32x4*)(p + 12);
      h16x8 o0, o1;
      o0[0]=(h16)v0[0]; o0[1]=(h16)v0[1]; o0[2]=(h16)v0[2]; o0[3]=(h16)v0[3];
      o0[4]=(h16)v1[0]; o0[5]=(h16)v1[1]; o0[6]=(h16)v1[2]; o0[7]=(h16)v1[3];
      o1[0]=(h16)v2[0]; o1[1]=(h16)v2[1]; o1[2]=(h16)v2[2]; o1[3]=(h16)v2[3];
      o1[4]=(h16)v3[0]; o1[5]=(h16)v3[1]; o1[6]=(h16)v3[2]; o1[7]=(h16)v3[3];
      *(h16x8*)&lA[r_local][kh]     = o0;
      *(h16x8*)&lA[r_local][kh + 8] = o1;
    }
    // stage B (f16 B^T, reg-staged)
    #pragma unroll
    for (int i = 0; i < 2; ++i){
      int flat = i * 256 + tid;
      int nl = flat >> 2, kq = flat & 3;
      uint4 w = *(const uint4*)(WxT + ((size_t)(bn0 + nl)) * Ii + k0 + kq * 8);
      *(uint4*)&lB[nl][kq * 8] = w;
    }
    __syncthreads();
    // fragments + MFMA
    h16x8 af[4], bfr[4];
    #pragma unroll
    for (int m = 0; m < 4; ++m)
      af[m] = *(const h16x8*)&lA[wm * 64 + m * 16 + (lane & 15)][(lane >> 4) * 8];
    #pragma unroll
    for (int n = 0; n < 4; ++n)
      bfr[n] = *(const h16x8*)&lB[wn * 64 + n * 16 + (lane & 15)][(lane >> 4) * 8];
    #pragma unroll
    for (int m = 0; m < 4; ++m)
      #pragma unroll
      for (int n = 0; n < 4; ++n)
        acc[m][n] = __builtin_amdgcn_mfma_f32_16x16x32_f16(af[m], bfr[n], acc[m][n], 0, 0, 0);
  }
  // epilogue: C row = (lane>>4)*4 + reg, col = lane&15 (verified layout)
  #pragma unroll
  for (int m = 0; m < 4; ++m){
    int rg = bm0 + wm * 64 + m * 16 + ((lane >> 4) << 2);
    #pragma unroll
    for (int n = 0; n < 4; ++n){
      int cg = bn0 + wn * 64 + n * 16 + (lane & 15);
      #pragma unroll
      for (int q = 0; q < 4; ++q)
        zx[(size_t)(rg + q) * G4 + cg] = acc[m][n][q];
    }
  }
}

// ---------------------------------------------------------------------------
// Recurrence: one block per batch, 1024 threads.
//  thread (j, hf): hf==0 -> z_i[j], z_f[j] ; hf==1 -> z_c[j], z_o[j]
//  W_h streamed from L2 in [g][col][8] f16 layout (fully coalesced uint4).
// ---------------------------------------------------------------------------
__global__ __launch_bounds__(1024) void lstm_rec(
    const float* __restrict__ zx, const uint4* __restrict__ Wpk4,
    const float* __restrict__ h0, const float* __restrict__ c0,
    const float* __restrict__ Wci, const float* __restrict__ Wcf, const float* __restrict__ Wco,
    const float* __restrict__ bi, const float* __restrict__ bfg, const float* __restrict__ bc,
    const float* __restrict__ bo,
    float* __restrict__ out, float* __restrict__ hT, float* __restrict__ cT,
    float* __restrict__ h_state, float* __restrict__ c_state,
    int t0, int Tc, int first, int last)
{
  __shared__ float sc_[Hh];
  __shared__ uint4 sh16[Hh / 8];     // h packed f16, 16B-aligned
  __shared__ float si[Hh], sf[Hh];

  const int b = blockIdx.x, tid = threadIdx.x;
  const int j  = tid & (Hh - 1);
  const int hf = tid >> 9;

  if (tid < Hh){
    float hv, cv;
    if (first){ hv = h0[b * Hh + tid]; cv = c0[b * Hh + tid]; }
    else      { hv = h_state[b * Hh + tid]; cv = c_state[b * Hh + tid]; }
    sc_[tid] = cv;
    ((h16*)sh16)[tid] = (h16)hv;
  }
  __syncthreads();

  const int col0 = hf * 1024 + j;      // hf0: z_i ; hf1: z_c
  const int col1 = col0 + 512;         // hf0: z_f ; hf1: z_o
  const uint4* w0p = Wpk4 + col0;
  const uint4* w1p = Wpk4 + col1;

  float last_hn = 0.f, last_cn = 0.f;

  for (int t = 0; t < Tc; ++t){
    const float* zrow = zx + ((size_t)b * Tc + t) * G4;
    float acc0 = 0.f, acc1 = 0.f;
    #pragma unroll 4
    for (int g = 0; g < 64; ++g){
      uint4 hv = sh16[g];                    // LDS broadcast
      uint4 w0 = w0p[(size_t)g * G4];        // coalesced 16B/lane
      uint4 w1 = w1p[(size_t)g * G4];
      acc0 = dot8(w0, hv, acc0);
      acc1 = dot8(w1, hv, acc1);
    }
    float z0 = zrow[col0] + acc0;
    float z1 = zrow[col1] + acc1;
    float cp = sc_[j];
    float tcv = 0.f, zo = 0.f;
    if (hf == 0){
      float iv = sigm(z0 + cp * Wci[j] + bi[j]);
      float fv = sigm(z1 + cp * Wcf[j] + bfg[j]);
      si[j] = iv; sf[j] = fv;
    } else {
      tcv = tanh_(z0 + bc[j]);
      zo = z1;
    }
    __syncthreads();
    if (hf == 1){
      float cn = sf[j] * cp + si[j] * tcv;
      float ov = sigm(zo + cn * Wco[j] + bo[j]);
      float hn = ov * tanh_(cn);
      sc_[j] = cn;
      ((h16*)sh16)[j] = (h16)hn;
      out[((size_t)b * Ss + (t0 + t)) * Hh + j] = hn;
      last_hn = hn; last_cn = cn;
    }
    __syncthreads();
  }
  if (hf == 1){
    h_state[b * Hh + j] = last_hn;
    c_state[b * Hh + j] = last_cn;
    if (last){ hT[b * Hh + j] = last_hn; cT[b * Hh + j] = last_cn; }
  }
}

// ---------------------------------------------------------------------------
extern "C" void kernel_launch(void* const* d_in, const int* in_sizes, int n_in,
                              void* d_out, int out_size, void* d_ws, size_t ws_size,
                              hipStream_t stream){
  const float* x   = (const float*)d_in[0];
  const float* h0  = (const float*)d_in[1];
  const float* c0  = (const float*)d_in[2];
  const float* Wxh = (const float*)d_in[3];
  const float* Wci = (const float*)d_in[4];
  const float* Wcf = (const float*)d_in[5];
  const float* Wco = (const float*)d_in[6];
  const float* bi  = (const float*)d_in[7];
  const float* bf  = (const float*)d_in[8];
  const float* bc  = (const float*)d_in[9];
  const float* bo  = (const float*)d_in[10];

  float* out = (float*)d_out;
  float* hT  = out + (size_t)Bb * Ss * Hh;
  float* cT  = hT + (size_t)Bb * Hh;

  uint8_t* ws = (uint8_t*)d_ws;
  size_t off = 0;
  auto take = [&](size_t bytes) -> uint8_t* {
    uint8_t* p = ws + off;
    off += (bytes + 255) & ~(size_t)255;
    return p;
  };
  h16* WxT      = (h16*)take((size_t)G4 * Ii * 2);
  h16* Wpk      = (h16*)take((size_t)G4 * Hh * 2);
  float* h_state = (float*)take((size_t)Bb * Hh * 4);
  float* c_state = (float*)take((size_t)Bb * Hh * 4);

  int Tc = Ss, tclog = 10;
  while (Tc > 2 && off + (size_t)Bb * Tc * G4 * 4 > ws_size){ Tc >>= 1; tclog--; }
  float* zxbuf = (float*)take((size_t)Bb * Tc * G4 * 4);

  prep_weights<<<(Ii + Hh) * G4 / 256, 256, 0, stream>>>(Wxh, WxT, Wpk);

  int nch = Ss / Tc;
  for (int c = 0; c < nch; ++c){
    int t0 = c * Tc;
    dim3 grid(G4 / BN, Bb * Tc / BM);
    gemm_zx<<<grid, 256, 0, stream>>>(x, WxT, zxbuf, t0, tclog);
    lstm_rec<<<Bb, 1024, 0, stream>>>(zxbuf, (const uint4*)Wpk, h0, c0,
                                      Wci, Wcf, Wco, bi, bf, bc, bo,
                                      out, hT, cT, h_state, c_state,
                                      t0, Tc, c == 0, c == nch - 1);
  }
}

// Round 2
// 9091.533 us; speedup vs baseline: 1.8661x; 1.8661x over previous
//
#include <hip/hip_runtime.h>
#include <hip/hip_fp16.h>
#include <stdint.h>
#include <stddef.h>

#define Bb 64
#define Ss 1024
#define Ii 512
#define Hh 512
#define G4 2048   // 4*H
#define NBK 64    // recurrence blocks
#define JPB 8     // hidden units per block

typedef _Float16 h16;
typedef _Float16 h16x8 __attribute__((ext_vector_type(8)));
typedef float    f32x4 __attribute__((ext_vector_type(4)));

__device__ __forceinline__ float sigm(float x){ return 1.0f / (1.0f + __expf(-x)); }
__device__ __forceinline__ float tanh_(float x){
  float e = __expf(-2.0f * fabsf(x));
  float t = (1.0f - e) / (1.0f + e);
  return copysignf(t, x);
}

// ---------------------------------------------------------------------------
// prep 1: WxT[n][k] = (f16) W_xh[k][n] for k < I  (B^T layout for gemm_zx)
// ---------------------------------------------------------------------------
__global__ void prep_weights(const float* __restrict__ Wxh, h16* __restrict__ WxT){
  int idx = blockIdx.x * 256 + threadIdx.x;
  if (idx >= Ii * G4) return;
  int k = idx / G4, n = idx % G4;
  WxT[(size_t)n * Ii + k] = (h16)Wxh[idx];
}

// ---------------------------------------------------------------------------
// prep 2: pack W_h into per-block register-fragment order + init h_buf + cnt.
//  Wr[d], d = (bk*32 + pk)*64 + l ; pk = n*16 + ks
//   element e: W_xh[I + ks*32 + (l>>4)*8 + e][ (cl>>3)*512 + bk*8 + (cl&7) ],
//   cl = n*16 + (l&15)
// ---------------------------------------------------------------------------
__global__ void prep_rec(const float* __restrict__ Wxh, uint4* __restrict__ Wr,
                         const float* __restrict__ h0g, h16* __restrict__ hbuf,
                         unsigned* __restrict__ cnt){
  int blk = blockIdx.x, tid = threadIdx.x;
  if (blk < 512){
    int d  = blk * 256 + tid;
    int l  = d & 63, pk = (d >> 6) & 31, bk = d >> 11;
    int n  = pk >> 4, ks = pk & 15;
    int k  = ks * 32 + (l >> 4) * 8;
    int cl = n * 16 + (l & 15);
    int col = (cl >> 3) * 512 + bk * JPB + (cl & 7);
    h16x8 v;
    #pragma unroll
    for (int e = 0; e < 8; ++e)
      v[e] = (h16)Wxh[(size_t)(Ii + k + e) * G4 + col];
    Wr[d] = *(uint4*)&v;
  } else {
    int t = (blk - 512) * 256 + tid;    // 0..1023
    #pragma unroll
    for (int i = 0; i < 32; ++i){
      int idx = t * 32 + i;             // covers 64*512 h16 of buffer 0
      hbuf[idx] = (h16)h0g[idx];
    }
    cnt[t] = 0;
  }
}

// ---------------------------------------------------------------------------
// zx GEMM (unchanged from R1): zx[r][n] = sum_k x_row(r)[k] * W_x[k][n]
// ---------------------------------------------------------------------------
#define BM 128
#define BN 128
#define BK 32
#define LDP 48

__global__ __launch_bounds__(256) void gemm_zx(const float* __restrict__ x,
                                               const h16* __restrict__ WxT,
                                               float* __restrict__ zx,
                                               int t0, int tclog){
  __shared__ h16 lA[BM][LDP];
  __shared__ h16 lB[BN][LDP];
  const int tid  = threadIdx.x;
  const int lane = tid & 63, wid = tid >> 6;
  const int wm = wid >> 1, wn = wid & 1;
  const int bn0 = blockIdx.x * BN, bm0 = blockIdx.y * BM;

  f32x4 acc[4][4] = {};

  const int r_local = tid >> 1;
  const int kh = (tid & 1) * 16;
  const int r = bm0 + r_local;
  const int bidx = r >> tclog;
  const int sc   = r & ((1 << tclog) - 1);
  const float* xrow = x + ((size_t)bidx * Ss + (t0 + sc)) * Ii + kh;

  for (int ks = 0; ks < Ii / BK; ++ks){
    const int k0 = ks * BK;
    __syncthreads();
    {
      const float* p = xrow + k0;
      f32x4 v0 = *(const f32x4*)(p);
      f32x4 v1 = *(const f32x4*)(p + 4);
      f32x4 v2 = *(const f32x4*)(p + 8);
      f32x4 v3 = *(const f32x4*)(p + 12);
      h16x8 o0, o1;
      o0[0]=(h16)v0[0]; o0[1]=(h16)v0[1]; o0[2]=(h16)v0[2]; o0[3]=(h16)v0[3];
      o0[4]=(h16)v1[0]; o0[5]=(h16)v1[1]; o0[6]=(h16)v1[2]; o0[7]=(h16)v1[3];
      o1[0]=(h16)v2[0]; o1[1]=(h16)v2[1]; o1[2]=(h16)v2[2]; o1[3]=(h16)v2[3];
      o1[4]=(h16)v3[0]; o1[5]=(h16)v3[1]; o1[6]=(h16)v3[2]; o1[7]=(h16)v3[3];
      *(h16x8*)&lA[r_local][kh]     = o0;
      *(h16x8*)&lA[r_local][kh + 8] = o1;
    }
    #pragma unroll
    for (int i = 0; i < 2; ++i){
      int flat = i * 256 + tid;
      int nl = flat >> 2, kq = flat & 3;
      uint4 w = *(const uint4*)(WxT + ((size_t)(bn0 + nl)) * Ii + k0 + kq * 8);
      *(uint4*)&lB[nl][kq * 8] = w;
    }
    __syncthreads();
    h16x8 af[4], bfr[4];
    #pragma unroll
    for (int m = 0; m < 4; ++m)
      af[m] = *(const h16x8*)&lA[wm * 64 + m * 16 + (lane & 15)][(lane >> 4) * 8];
    #pragma unroll
    for (int n = 0; n < 4; ++n)
      bfr[n] = *(const h16x8*)&lB[wn * 64 + n * 16 + (lane & 15)][(lane >> 4) * 8];
    #pragma unroll
    for (int m = 0; m < 4; ++m)
      #pragma unroll
      for (int n = 0; n < 4; ++n)
        acc[m][n] = __builtin_amdgcn_mfma_f32_16x16x32_f16(af[m], bfr[n], acc[m][n], 0, 0, 0);
  }
  #pragma unroll
  for (int m = 0; m < 4; ++m){
    int rg = bm0 + wm * 64 + m * 16 + ((lane >> 4) << 2);
    #pragma unroll
    for (int n = 0; n < 4; ++n){
      int cg = bn0 + wn * 64 + n * 16 + (lane & 15);
      #pragma unroll
      for (int q = 0; q < 4; ++q)
        zx[(size_t)(rg + q) * G4 + cg] = acc[m][n][q];
    }
  }
}

// ---------------------------------------------------------------------------
// Recurrence v2: 64 blocks x 256 threads. Block bk owns hidden units
// [bk*8, bk*8+8) -> 32 gate columns, weights register-resident.
// Wave w computes batches [16w,16w+16) over full K=512 via MFMA.
// Cross-block h exchange through double-buffered global h_buf + per-step
// device-scope counters.
// ---------------------------------------------------------------------------
__global__ __launch_bounds__(256, 1) void lstm_rec2(
    const float* __restrict__ zx, const uint4* __restrict__ Wr,
    h16* __restrict__ hbuf, unsigned* __restrict__ cnt,
    const float* __restrict__ c0g, float* __restrict__ c_state,
    const float* __restrict__ Wci, const float* __restrict__ Wcf, const float* __restrict__ Wco,
    const float* __restrict__ bi, const float* __restrict__ bfg, const float* __restrict__ bc,
    const float* __restrict__ bo,
    float* __restrict__ out, float* __restrict__ hT, float* __restrict__ cT,
    int t0, int Tc, int first, int last)
{
  __shared__ float zf[64 * 33];
  __shared__ float szp[64 * 36];

  const int bk = blockIdx.x, tid = threadIdx.x;
  const int l = tid & 63, w = tid >> 6;
  const int jl = tid & 7, b0 = tid >> 3;          // pairs: (b0, b0+32) x jl
  const int jg = bk * JPB + jl;

  const float wci = Wci[jg], wcf = Wcf[jg], wco = Wco[jg];
  const float vbi = bi[jg], vbf = bfg[jg], vbc = bc[jg], vbo = bo[jg];

  float cA, cB;
  if (first){ cA = c0g[b0 * Hh + jg]; cB = c0g[(b0 + 32) * Hh + jg]; }
  else      { cA = c_state[b0 * Hh + jg]; cB = c_state[(b0 + 32) * Hh + jg]; }

  // --- register-resident W_h fragments (32 KB/block, loaded once) ---
  h16x8 bfr[32];
  {
    const uint4* p = Wr + (size_t)bk * 2048 + l;
    #pragma unroll
    for (int pk = 0; pk < 32; ++pk){
      uint4 t = p[(size_t)pk * 64];
      bfr[pk] = *(h16x8*)&t;
    }
  }

  // --- zx prologue: thread (bz, gz) owns an 8-float gate run ---
  const int bz = tid >> 2, gz = tid & 3;
  const float* zxbase = zx + (size_t)bz * Tc * G4 + gz * 512 + bk * JPB;
  float4 zc0 = *(const float4*)(zxbase);
  float4 zc1 = *(const float4*)(zxbase + 4);

  const int arow = w * 16 + (l & 15);
  const int acol = (l >> 4) * 8;
  const int crow = w * 16 + (l >> 4) * 4;

  for (int s = 0; s < Tc; ++s){
    const int gs = t0 + s;
    const int par = gs & 1;

    // prefetch next step's zx (independent of flags)
    float4 zn0, zn1;
    if (s + 1 < Tc){
      const float* p = zxbase + (size_t)(s + 1) * G4;
      zn0 = *(const float4*)p; zn1 = *(const float4*)(p + 4);
    }

    if (gs > 0){
      if (tid == 0){
        while (__hip_atomic_load(&cnt[gs - 1], __ATOMIC_RELAXED,
                                 __HIP_MEMORY_SCOPE_AGENT) != (unsigned)NBK) {}
      }
      __syncthreads();
      __builtin_amdgcn_fence(__ATOMIC_ACQUIRE, "agent");
    }

    // stage zx into LDS
    *(float4*)&szp[bz * 36 + gz * 8]     = zc0;
    *(float4*)&szp[bz * 36 + gz * 8 + 4] = zc1;

    // h fragments + MFMA (K=512, 2 N-tiles)
    f32x4 acc0 = {0.f,0.f,0.f,0.f}, acc1 = {0.f,0.f,0.f,0.f};
    const h16* hp = hbuf + par * (Bb * Hh) + arow * Hh + acol;
    #pragma unroll
    for (int kc = 0; kc < 4; ++kc){
      h16x8 a[4];
      #pragma unroll
      for (int i = 0; i < 4; ++i)
        a[i] = *(const h16x8*)(hp + (kc * 4 + i) * 32);
      #pragma unroll
      for (int i = 0; i < 4; ++i){
        acc0 = __builtin_amdgcn_mfma_f32_16x16x32_f16(a[i], bfr[kc * 4 + i],      acc0, 0, 0, 0);
        acc1 = __builtin_amdgcn_mfma_f32_16x16x32_f16(a[i], bfr[16 + kc * 4 + i], acc1, 0, 0, 0);
      }
    }

    // z partials -> LDS  (C layout: row=(l>>4)*4+q, col=l&15)
    #pragma unroll
    for (int q = 0; q < 4; ++q){
      zf[(crow + q) * 33 + (l & 15)]      = acc0[q];
      zf[(crow + q) * 33 + 16 + (l & 15)] = acc1[q];
    }
    __syncthreads();

    // gates for the 2 (b, jl) pairs
    #pragma unroll
    for (int pr = 0; pr < 2; ++pr){
      const int b = b0 + pr * 32;
      float cp = pr ? cB : cA;
      float z_i = szp[b * 36 + jl]      + zf[b * 33 + jl];
      float z_f = szp[b * 36 + 8 + jl]  + zf[b * 33 + 8 + jl];
      float z_c = szp[b * 36 + 16 + jl] + zf[b * 33 + 16 + jl];
      float z_o = szp[b * 36 + 24 + jl] + zf[b * 33 + 24 + jl];
      float iv = sigm(z_i + cp * wci + vbi);
      float fv = sigm(z_f + cp * wcf + vbf);
      float cn = fv * cp + iv * tanh_(z_c + vbc);
      float ov = sigm(z_o + cn * wco + vbo);
      float hn = ov * tanh_(cn);
      if (pr) cB = cn; else cA = cn;
      out[((size_t)b * Ss + gs) * Hh + jg] = hn;
      hbuf[(par ^ 1) * (Bb * Hh) + b * Hh + jg] = (h16)hn;
      if (last && s == Tc - 1){ hT[b * Hh + jg] = hn; cT[b * Hh + jg] = cn; }
    }
    __syncthreads();   // drains vmcnt: all h stores complete before signal

    if (tid == 0){
      __builtin_amdgcn_fence(__ATOMIC_RELEASE, "agent");
      __hip_atomic_fetch_add(&cnt[gs], 1u, __ATOMIC_RELAXED, __HIP_MEMORY_SCOPE_AGENT);
    }
    zc0 = zn0; zc1 = zn1;
  }

  c_state[b0 * Hh + jg] = cA;
  c_state[(b0 + 32) * Hh + jg] = cB;
}

// ---------------------------------------------------------------------------
extern "C" void kernel_launch(void* const* d_in, const int* in_sizes, int n_in,
                              void* d_out, int out_size, void* d_ws, size_t ws_size,
                              hipStream_t stream){
  const float* x   = (const float*)d_in[0];
  const float* h0  = (const float*)d_in[1];
  const float* c0  = (const float*)d_in[2];
  const float* Wxh = (const float*)d_in[3];
  const float* Wci = (const float*)d_in[4];
  const float* Wcf = (const float*)d_in[5];
  const float* Wco = (const float*)d_in[6];
  const float* bi  = (const float*)d_in[7];
  const float* bf  = (const float*)d_in[8];
  const float* bc  = (const float*)d_in[9];
  const float* bo  = (const float*)d_in[10];

  float* out = (float*)d_out;
  float* hT  = out + (size_t)Bb * Ss * Hh;
  float* cT  = hT + (size_t)Bb * Hh;

  uint8_t* ws = (uint8_t*)d_ws;
  size_t off = 0;
  auto take = [&](size_t bytes) -> uint8_t* {
    uint8_t* p = ws + off;
    off += (bytes + 255) & ~(size_t)255;
    return p;
  };
  h16*      WxT     = (h16*)take((size_t)G4 * Ii * 2);
  uint4*    Wr      = (uint4*)take((size_t)G4 * Hh * 2);
  h16*      hbuf    = (h16*)take((size_t)2 * Bb * Hh * 2);
  unsigned* cnt     = (unsigned*)take((size_t)Ss * 4);
  float*    c_state = (float*)take((size_t)Bb * Hh * 4);

  int Tc = Ss, tclog = 10;
  while (Tc > 2 && off + (size_t)Bb * Tc * G4 * 4 > ws_size){ Tc >>= 1; tclog--; }
  float* zxbuf = (float*)take((size_t)Bb * Tc * G4 * 4);

  prep_weights<<<(Ii * G4) / 256, 256, 0, stream>>>(Wxh, WxT);
  prep_rec<<<516, 256, 0, stream>>>(Wxh, Wr, h0, hbuf, cnt);

  int nch = Ss / Tc;
  for (int c = 0; c < nch; ++c){
    int t0 = c * Tc;
    dim3 grid(G4 / BN, Bb * Tc / BM);
    gemm_zx<<<grid, 256, 0, stream>>>(x, WxT, zxbuf, t0, tclog);
    lstm_rec2<<<NBK, 256, 0, stream>>>(zxbuf, Wr, hbuf, cnt, c0, c_state,
                                       Wci, Wcf, Wco, bi, bf, bc, bo,
                                       out, hT, cT, t0, Tc, c == 0, c == nch - 1);
  }
}

// Round 4
// 5434.643 us; speedup vs baseline: 3.1218x; 1.6729x over previous
//
#include <hip/hip_runtime.h>
#include <hip/hip_fp16.h>
#include <stdint.h>
#include <stddef.h>

#define Bb 64
#define Ss 1024
#define Ii 512
#define Hh 512
#define G4 2048   // 4*H
#define NBK 64    // recurrence blocks
#define JPB 8     // hidden units per block

typedef _Float16 h16;
typedef _Float16 h16x8 __attribute__((ext_vector_type(8)));
typedef float    f32x4 __attribute__((ext_vector_type(4)));
typedef unsigned u32x4 __attribute__((ext_vector_type(4)));   // native, asm-legal

__device__ __forceinline__ float sigm(float x){ return 1.0f / (1.0f + __expf(-x)); }
__device__ __forceinline__ float tanh_(float x){
  float e = __expf(-2.0f * fabsf(x));
  float t = (1.0f - e) / (1.0f + e);
  return copysignf(t, x);
}

// device-coherent 16B accesses: bypass L1+L2, served at device coherence point
__device__ __forceinline__ u32x4 load_coh16(const void* p){
  u32x4 r;
  asm volatile("global_load_dwordx4 %0, %1, off sc0 sc1"
               : "=v"(r) : "v"(p) : "memory");
  return r;
}
__device__ __forceinline__ void store_coh16(void* p, u32x4 v){
  asm volatile("global_store_dwordx4 %0, %1, off sc0 sc1"
               :: "v"(p), "v"(v) : "memory");
}

// ---------------------------------------------------------------------------
// prep 1: WxT[n][k] = (f16) W_xh[k][n] for k < I  (B^T layout for gemm_zx)
// ---------------------------------------------------------------------------
__global__ void prep_weights(const float* __restrict__ Wxh, h16* __restrict__ WxT){
  int idx = blockIdx.x * 256 + threadIdx.x;
  if (idx >= Ii * G4) return;
  int k = idx / G4, n = idx % G4;
  WxT[(size_t)n * Ii + k] = (h16)Wxh[idx];
}

// ---------------------------------------------------------------------------
// prep 2: pack W_h into per-block register-fragment order + init h_buf + cnt.
// ---------------------------------------------------------------------------
__global__ void prep_rec(const float* __restrict__ Wxh, u32x4* __restrict__ Wr,
                         const float* __restrict__ h0g, h16* __restrict__ hbuf,
                         unsigned* __restrict__ cnt){
  int blk = blockIdx.x, tid = threadIdx.x;
  if (blk < 512){
    int d  = blk * 256 + tid;
    int l  = d & 63, pk = (d >> 6) & 31, bk = d >> 11;
    int n  = pk >> 4, ks = pk & 15;
    int k  = ks * 32 + (l >> 4) * 8;
    int cl = n * 16 + (l & 15);
    int col = (cl >> 3) * 512 + bk * JPB + (cl & 7);
    h16x8 v;
    #pragma unroll
    for (int e = 0; e < 8; ++e)
      v[e] = (h16)Wxh[(size_t)(Ii + k + e) * G4 + col];
    Wr[d] = *(u32x4*)&v;
  } else {
    int t = (blk - 512) * 256 + tid;    // 0..1023
    #pragma unroll
    for (int i = 0; i < 32; ++i){
      int idx = t * 32 + i;             // covers 64*512 h16 of buffer 0
      hbuf[idx] = (h16)h0g[idx];
    }
    __hip_atomic_store(&cnt[t], 0u, __ATOMIC_RELAXED, __HIP_MEMORY_SCOPE_AGENT);
  }
}

// ---------------------------------------------------------------------------
// zx GEMM (unchanged): zx[r][n] = sum_k x_row(r)[k] * W_x[k][n]
// ---------------------------------------------------------------------------
#define BM 128
#define BN 128
#define BK 32
#define LDP 48

__global__ __launch_bounds__(256) void gemm_zx(const float* __restrict__ x,
                                               const h16* __restrict__ WxT,
                                               float* __restrict__ zx,
                                               int t0, int tclog){
  __shared__ h16 lA[BM][LDP];
  __shared__ h16 lB[BN][LDP];
  const int tid  = threadIdx.x;
  const int lane = tid & 63, wid = tid >> 6;
  const int wm = wid >> 1, wn = wid & 1;
  const int bn0 = blockIdx.x * BN, bm0 = blockIdx.y * BM;

  f32x4 acc[4][4] = {};

  const int r_local = tid >> 1;
  const int kh = (tid & 1) * 16;
  const int r = bm0 + r_local;
  const int bidx = r >> tclog;
  const int sc   = r & ((1 << tclog) - 1);
  const float* xrow = x + ((size_t)bidx * Ss + (t0 + sc)) * Ii + kh;

  for (int ks = 0; ks < Ii / BK; ++ks){
    const int k0 = ks * BK;
    __syncthreads();
    {
      const float* p = xrow + k0;
      f32x4 v0 = *(const f32x4*)(p);
      f32x4 v1 = *(const f32x4*)(p + 4);
      f32x4 v2 = *(const f32x4*)(p + 8);
      f32x4 v3 = *(const f32x4*)(p + 12);
      h16x8 o0, o1;
      o0[0]=(h16)v0[0]; o0[1]=(h16)v0[1]; o0[2]=(h16)v0[2]; o0[3]=(h16)v0[3];
      o0[4]=(h16)v1[0]; o0[5]=(h16)v1[1]; o0[6]=(h16)v1[2]; o0[7]=(h16)v1[3];
      o1[0]=(h16)v2[0]; o1[1]=(h16)v2[1]; o1[2]=(h16)v2[2]; o1[3]=(h16)v2[3];
      o1[4]=(h16)v3[0]; o1[5]=(h16)v3[1]; o1[6]=(h16)v3[2]; o1[7]=(h16)v3[3];
      *(h16x8*)&lA[r_local][kh]     = o0;
      *(h16x8*)&lA[r_local][kh + 8] = o1;
    }
    #pragma unroll
    for (int i = 0; i < 2; ++i){
      int flat = i * 256 + tid;
      int nl = flat >> 2, kq = flat & 3;
      u32x4 w = *(const u32x4*)(WxT + ((size_t)(bn0 + nl)) * Ii + k0 + kq * 8);
      *(u32x4*)&lB[nl][kq * 8] = w;
    }
    __syncthreads();
    h16x8 af[4], bfr[4];
    #pragma unroll
    for (int m = 0; m < 4; ++m)
      af[m] = *(const h16x8*)&lA[wm * 64 + m * 16 + (lane & 15)][(lane >> 4) * 8];
    #pragma unroll
    for (int n = 0; n < 4; ++n)
      bfr[n] = *(const h16x8*)&lB[wn * 64 + n * 16 + (lane & 15)][(lane >> 4) * 8];
    #pragma unroll
    for (int m = 0; m < 4; ++m)
      #pragma unroll
      for (int n = 0; n < 4; ++n)
        acc[m][n] = __builtin_amdgcn_mfma_f32_16x16x32_f16(af[m], bfr[n], acc[m][n], 0, 0, 0);
  }
  #pragma unroll
  for (int m = 0; m < 4; ++m){
    int rg = bm0 + wm * 64 + m * 16 + ((lane >> 4) << 2);
    #pragma unroll
    for (int n = 0; n < 4; ++n){
      int cg = bn0 + wn * 64 + n * 16 + (lane & 15);
      #pragma unroll
      for (int q = 0; q < 4; ++q)
        zx[(size_t)(rg + q) * G4 + cg] = acc[m][n][q];
    }
  }
}

// ---------------------------------------------------------------------------
// Recurrence v3: 64 blocks x 256 threads, weights pinned in VGPRs,
// h exchanged via device-coherent (sc0 sc1) 16B accesses, per-step
// relaxed agent-scope counter. No cache-wide fences anywhere.
// ---------------------------------------------------------------------------
__global__ __launch_bounds__(256, 1) void lstm_rec2(
    const float* __restrict__ zx, const u32x4* __restrict__ Wr,
    h16* __restrict__ hbuf, unsigned* __restrict__ cnt,
    const float* __restrict__ c0g, float* __restrict__ c_state,
    const float* __restrict__ Wci, const float* __restrict__ Wcf, const float* __restrict__ Wco,
    const float* __restrict__ bi, const float* __restrict__ bfg, const float* __restrict__ bc,
    const float* __restrict__ bo,
    float* __restrict__ out, float* __restrict__ hT, float* __restrict__ cT,
    int t0, int Tc, int first, int last)
{
  __shared__ float zf[64 * 33];
  __shared__ float szp[64 * 36];
  __shared__ h16   hx[64 * 8];

  const int bk = blockIdx.x, tid = threadIdx.x;
  const int l = tid & 63, w = tid >> 6;
  const int jl = tid & 7, b0 = tid >> 3;          // pairs: (b0, b0+32) x jl
  const int jg = bk * JPB + jl;

  const float wci = Wci[jg], wcf = Wcf[jg], wco = Wco[jg];
  const float vbi = bi[jg], vbf = bfg[jg], vbc = bc[jg], vbo = bo[jg];

  float cA, cB;
  if (first){ cA = c0g[b0 * Hh + jg]; cB = c0g[(b0 + 32) * Hh + jg]; }
  else      { cA = c_state[b0 * Hh + jg]; cB = c_state[(b0 + 32) * Hh + jg]; }

  // --- register-resident W_h fragments (32 KB/block), pinned against remat ---
  h16x8 bfr[32];
  {
    const u32x4* p = Wr + (size_t)bk * 2048 + l;
    #pragma unroll
    for (int pk = 0; pk < 32; ++pk){
      u32x4 t = p[(size_t)pk * 64];
      bfr[pk] = *(h16x8*)&t;
    }
  }
  #pragma unroll
  for (int pk = 0; pk < 32; ++pk)
    asm volatile("" : "+v"(bfr[pk]));

  // --- zx prologue: thread (bz, gz) owns an 8-float gate run ---
  const int bz = tid >> 2, gz = tid & 3;
  const float* zxbase = zx + (size_t)bz * Tc * G4 + gz * 512 + bk * JPB;
  float4 zc0 = *(const float4*)(zxbase);
  float4 zc1 = *(const float4*)(zxbase + 4);

  const int arow = w * 16 + (l & 15);
  const int acol = (l >> 4) * 8;
  const int crow = w * 16 + (l >> 4) * 4;

  for (int s = 0; s < Tc; ++s){
    const int gs = t0 + s;
    const int par = gs & 1;

    // prefetch next step's zx (plain, L2-cached)
    float4 zn0, zn1;
    if (s + 1 < Tc){
      const float* p = zxbase + (size_t)(s + 1) * G4;
      zn0 = *(const float4*)p; zn1 = *(const float4*)(p + 4);
    }

    if (gs > 0 && tid == 0){
      while (__hip_atomic_load(&cnt[gs - 1], __ATOMIC_RELAXED,
                               __HIP_MEMORY_SCOPE_AGENT) != (unsigned)NBK) {}
    }
    __syncthreads();                                    // (1) release spin

    // issue coherent h loads (MALL), overlap with szp staging
    u32x4 hr[16];
    const h16* hp = hbuf + par * (Bb * Hh) + arow * Hh + acol;
    #pragma unroll
    for (int pk = 0; pk < 16; ++pk)
      hr[pk] = load_coh16(hp + pk * 32);

    *(float4*)&szp[bz * 36 + gz * 8]     = zc0;
    *(float4*)&szp[bz * 36 + gz * 8 + 4] = zc1;

    asm volatile("s_waitcnt vmcnt(8)" ::: "memory");
    __builtin_amdgcn_sched_barrier(0);
    f32x4 acc0 = {0.f,0.f,0.f,0.f}, acc1 = {0.f,0.f,0.f,0.f};
    #pragma unroll
    for (int pk = 0; pk < 8; ++pk){
      h16x8 a = *(h16x8*)&hr[pk];
      acc0 = __builtin_amdgcn_mfma_f32_16x16x32_f16(a, bfr[pk],      acc0, 0, 0, 0);
      acc1 = __builtin_amdgcn_mfma_f32_16x16x32_f16(a, bfr[16 + pk], acc1, 0, 0, 0);
    }
    asm volatile("s_waitcnt vmcnt(0)" ::: "memory");
    __builtin_amdgcn_sched_barrier(0);
    #pragma unroll
    for (int pk = 8; pk < 16; ++pk){
      h16x8 a = *(h16x8*)&hr[pk];
      acc0 = __builtin_amdgcn_mfma_f32_16x16x32_f16(a, bfr[pk],      acc0, 0, 0, 0);
      acc1 = __builtin_amdgcn_mfma_f32_16x16x32_f16(a, bfr[16 + pk], acc1, 0, 0, 0);
    }

    // z partials -> LDS  (C layout: row=(l>>4)*4+q, col=l&15)
    #pragma unroll
    for (int q = 0; q < 4; ++q){
      zf[(crow + q) * 33 + (l & 15)]      = acc0[q];
      zf[(crow + q) * 33 + 16 + (l & 15)] = acc1[q];
    }
    __syncthreads();                                    // (2)

    // gates for the 2 (b, jl) pairs
    #pragma unroll
    for (int pr = 0; pr < 2; ++pr){
      const int b = b0 + pr * 32;
      float cp = pr ? cB : cA;
      float z_i = szp[b * 36 + jl]      + zf[b * 33 + jl];
      float z_f = szp[b * 36 + 8 + jl]  + zf[b * 33 + 8 + jl];
      float z_c = szp[b * 36 + 16 + jl] + zf[b * 33 + 16 + jl];
      float z_o = szp[b * 36 + 24 + jl] + zf[b * 33 + 24 + jl];
      float iv = sigm(z_i + cp * wci + vbi);
      float fv = sigm(z_f + cp * wcf + vbf);
      float cn = fv * cp + iv * tanh_(z_c + vbc);
      float ov = sigm(z_o + cn * wco + vbo);
      float hn = ov * tanh_(cn);
      if (pr) cB = cn; else cA = cn;
      out[((size_t)b * Ss + gs) * Hh + jg] = hn;
      hx[b * 8 + jl] = (h16)hn;
      if (last && s == Tc - 1){ hT[b * Hh + jg] = hn; cT[b * Hh + jg] = cn; }
    }
    __syncthreads();                                    // (3)

    if (tid < 64){
      u32x4 hv = *(u32x4*)&hx[tid * 8];
      store_coh16(hbuf + (par ^ 1) * (Bb * Hh) + tid * Hh + bk * JPB, hv);
      asm volatile("s_waitcnt vmcnt(0)" ::: "memory");  // h at coherence point
    }
    __syncthreads();                                    // (4)
    if (tid == 0)
      __hip_atomic_fetch_add(&cnt[gs], 1u, __ATOMIC_RELAXED, __HIP_MEMORY_SCOPE_AGENT);

    zc0 = zn0; zc1 = zn1;
  }

  c_state[b0 * Hh + jg] = cA;
  c_state[(b0 + 32) * Hh + jg] = cB;
}

// ---------------------------------------------------------------------------
extern "C" void kernel_launch(void* const* d_in, const int* in_sizes, int n_in,
                              void* d_out, int out_size, void* d_ws, size_t ws_size,
                              hipStream_t stream){
  const float* x   = (const float*)d_in[0];
  const float* h0  = (const float*)d_in[1];
  const float* c0  = (const float*)d_in[2];
  const float* Wxh = (const float*)d_in[3];
  const float* Wci = (const float*)d_in[4];
  const float* Wcf = (const float*)d_in[5];
  const float* Wco = (const float*)d_in[6];
  const float* bi  = (const float*)d_in[7];
  const float* bf  = (const float*)d_in[8];
  const float* bc  = (const float*)d_in[9];
  const float* bo  = (const float*)d_in[10];

  float* out = (float*)d_out;
  float* hT  = out + (size_t)Bb * Ss * Hh;
  float* cT  = hT + (size_t)Bb * Hh;

  uint8_t* ws = (uint8_t*)d_ws;
  size_t off = 0;
  auto take = [&](size_t bytes) -> uint8_t* {
    uint8_t* p = ws + off;
    off += (bytes + 255) & ~(size_t)255;
    return p;
  };
  h16*      WxT     = (h16*)take((size_t)G4 * Ii * 2);
  u32x4*    Wr      = (u32x4*)take((size_t)G4 * Hh * 2);
  h16*      hbuf    = (h16*)take((size_t)2 * Bb * Hh * 2);
  unsigned* cnt     = (unsigned*)take((size_t)Ss * 4);
  float*    c_state = (float*)take((size_t)Bb * Hh * 4);

  int Tc = Ss, tclog = 10;
  while (Tc > 2 && off + (size_t)Bb * Tc * G4 * 4 > ws_size){ Tc >>= 1; tclog--; }
  float* zxbuf = (float*)take((size_t)Bb * Tc * G4 * 4);

  prep_weights<<<(Ii * G4) / 256, 256, 0, stream>>>(Wxh, WxT);
  prep_rec<<<516, 256, 0, stream>>>(Wxh, Wr, h0, hbuf, cnt);

  int nch = Ss / Tc;
  for (int c = 0; c < nch; ++c){
    int t0 = c * Tc;
    dim3 grid(G4 / BN, Bb * Tc / BM);
    gemm_zx<<<grid, 256, 0, stream>>>(x, WxT, zxbuf, t0, tclog);
    lstm_rec2<<<NBK, 256, 0, stream>>>(zxbuf, Wr, hbuf, cnt, c0, c_state,
                                       Wci, Wcf, Wco, bi, bf, bc, bo,
                                       out, hT, cT, t0, Tc, c == 0, c == nch - 1);
  }
}